// Round 1
// baseline (4578.650 us; speedup 1.0000x reference)
//
#include <hip/hip_runtime.h>
#include <math.h>

typedef _Float16 half8  __attribute__((ext_vector_type(8)));
typedef float    floatx4 __attribute__((ext_vector_type(4)));

#define MFMA16(a, b, c) __builtin_amdgcn_mfma_f32_16x16x32_f16((a), (b), (c), 0, 0, 0)

// ---------------- workspace layout (bytes) ----------------
constexpr unsigned WBIG_OFF = 0;          // f16 [736][224]  rows: 0..207 Wr, 208..415 Wz, 416..623 Wn, 624..735 dec_w1
constexpr unsigned W2_OFF   = 329728;     // f16 [64][128]   dec_w2^ (row=y2col, col=k)
constexpr unsigned WE1_OFF  = 346112;     // f16 [112][224]  enc_w1
constexpr unsigned WE2_OFF  = 396288;     // f16 [208][128]  enc_w2
constexpr unsigned WEL_OFF  = 449536;     // f16 [208][224]  enc_wl
constexpr unsigned WIHC_OFF = 542720;     // f32 [624]  w_ih column (gate-padded)
constexpr unsigned BSUM_OFF = 545216;     // f32 [624]  r,z: b_ih+b_hh ; n: b_ih
constexpr unsigned BHHN_OFF = 547712;     // f32 [208]  b_hh (n gate)
constexpr unsigned B1P_OFF  = 548544;     // f32 [112]
constexpr unsigned B2P_OFF  = 548992;     // f32 [64]
constexpr unsigned W3P_OFF  = 549248;     // f32 [64]
constexpr unsigned BE1_OFF  = 549504;     // f32 [112]
constexpr unsigned BE2_OFF  = 549952;     // f32 [208]
constexpr unsigned BEL_OFF  = 550784;     // f32 [208]
constexpr unsigned B3_OFF   = 551616;     // f32 [1] (+pad)
constexpr unsigned CT_OFF   = 551632;     // f64 [100][2] twiddles (cos,sin)/100, exact zeros forced
constexpr unsigned WS_NEED  = 553232;

// ---------------- LDS layout (bytes) ----------------
// decoder:  Hb  f16 [256][212] @0 (108544) | Y1 f16 [256][104] @108544 (53248) | DECIN f32[256] @161792
// encoder:  XF  f32 [64][101]  @108544     | X1 f16 [64][104]  @108544 (after DFT)
//           SIG f16 [64][212]  @134400 (27136; X2 overlays after enc1) | CT f64[200] @161536
constexpr unsigned SMEM_BYTES = 163136;

__device__ __forceinline__ half8 lds_frag(const _Float16* p) {
  // 16B at 8B alignment -> two ds_read_b64 (stride 212*2=424B keeps banks uniform)
  union { uint2 u[2]; half8 h; } cv;
  cv.u[0] = *(const uint2*)p;
  cv.u[1] = *(const uint2*)(p + 4);
  return cv.h;
}
__device__ __forceinline__ half8 g_frag(const _Float16* p) {
  union { uint4 u; half8 h; } cv;
  cv.u = *(const uint4*)p;      // global_load_dwordx4 (rows are 16B aligned)
  return cv.h;
}
__device__ __forceinline__ float sigm(float x) {
  return __builtin_amdgcn_rcpf(1.f + __builtin_amdgcn_exp2f(-1.44269504f * x));
}
__device__ __forceinline__ float tanh_(float x) {
  return 1.f - 2.f * __builtin_amdgcn_rcpf(1.f + __builtin_amdgcn_exp2f(2.88539008f * x));
}

// =================== prep: pack weights to fp16, build twiddles ===================
__global__ __launch_bounds__(256) void prep_kernel(
    const float* __restrict__ enc_w1, const float* __restrict__ enc_b1,
    const float* __restrict__ enc_w2, const float* __restrict__ enc_b2,
    const float* __restrict__ enc_wl, const float* __restrict__ enc_bl,
    const float* __restrict__ w_ih,  const float* __restrict__ w_hh,
    const float* __restrict__ b_ih,  const float* __restrict__ b_hh,
    const float* __restrict__ dw1, const float* __restrict__ db1,
    const float* __restrict__ dw2, const float* __restrict__ db2,
    const float* __restrict__ dw3, const float* __restrict__ db3,
    unsigned char* __restrict__ ws)
{
  const int g = blockIdx.x * blockDim.x + threadIdx.x;
  const int st = gridDim.x * blockDim.x;
  _Float16* Wbig = (_Float16*)(ws + WBIG_OFF);
  for (int i = g; i < 736 * 224; i += st) {
    int row = i / 224, k = i - row * 224;
    float v = 0.f;
    if (k < 200) {
      if (row < 624) { int gg = row / 208, j = row - gg * 208;
        if (j < 200) v = w_hh[(gg * 200 + j) * 200 + k]; }
      else { int j = row - 624; if (j < 100) v = dw1[j * 200 + k]; }
    }
    Wbig[i] = (_Float16)v;
  }
  _Float16* W2 = (_Float16*)(ws + W2_OFF);
  for (int i = g; i < 64 * 128; i += st) {
    int r = i / 128, k = i - r * 128;
    W2[i] = (_Float16)((r < 50 && k < 100) ? dw2[r * 100 + k] : 0.f);
  }
  _Float16* We1 = (_Float16*)(ws + WE1_OFF);
  for (int i = g; i < 112 * 224; i += st) {
    int r = i / 224, k = i - r * 224;
    We1[i] = (_Float16)((r < 100 && k < 202) ? enc_w1[r * 202 + k] : 0.f);
  }
  _Float16* We2 = (_Float16*)(ws + WE2_OFF);
  for (int i = g; i < 208 * 128; i += st) {
    int r = i / 128, k = i - r * 128;
    We2[i] = (_Float16)((r < 202 && k < 100) ? enc_w2[r * 100 + k] : 0.f);
  }
  _Float16* Wel = (_Float16*)(ws + WEL_OFF);
  for (int i = g; i < 208 * 224; i += st) {
    int r = i / 224, k = i - r * 224;
    Wel[i] = (_Float16)((r < 200 && k < 202) ? enc_wl[r * 202 + k] : 0.f);
  }
  float* wihc = (float*)(ws + WIHC_OFF);
  float* bsum = (float*)(ws + BSUM_OFF);
  for (int i = g; i < 624; i += st) {
    int gg = i / 208, j = i - gg * 208;
    wihc[i] = (j < 200) ? w_ih[gg * 200 + j] : 0.f;
    float b = 0.f;
    if (j < 200) b = (gg < 2) ? (b_ih[gg * 200 + j] + b_hh[gg * 200 + j]) : b_ih[400 + j];
    bsum[i] = b;
  }
  float* bhhn = (float*)(ws + BHHN_OFF);
  for (int i = g; i < 208; i += st) bhhn[i] = (i < 200) ? b_hh[400 + i] : 0.f;
  float* b1p = (float*)(ws + B1P_OFF);
  for (int i = g; i < 112; i += st) b1p[i] = (i < 100) ? db1[i] : 0.f;
  float* b2p = (float*)(ws + B2P_OFF);
  for (int i = g; i < 64; i += st) b2p[i] = (i < 50) ? db2[i] : 0.f;
  float* w3p = (float*)(ws + W3P_OFF);
  for (int i = g; i < 64; i += st) w3p[i] = (i < 50) ? dw3[i] : 0.f;
  float* be1 = (float*)(ws + BE1_OFF);
  for (int i = g; i < 112; i += st) be1[i] = (i < 100) ? enc_b1[i] : 0.f;
  float* be2 = (float*)(ws + BE2_OFF);
  for (int i = g; i < 208; i += st) be2[i] = (i < 202) ? enc_b2[i] : 0.f;
  float* bel = (float*)(ws + BEL_OFF);
  for (int i = g; i < 208; i += st) bel[i] = (i < 200) ? enc_bl[i] : 0.f;
  if (g == 0) *(float*)(ws + B3_OFF) = db3[0];
  double* ct = (double*)(ws + CT_OFF);
  for (int m = g; m < 100; m += st) {
    double c, s;
    if      (m == 0)  { c = 1.0;  s = 0.0; }
    else if (m == 25) { c = 0.0;  s = -1.0; }
    else if (m == 50) { c = -1.0; s = 0.0; }
    else if (m == 75) { c = 0.0;  s = 1.0; }
    else { double a = -2.0 * 3.14159265358979323846 * (double)m / 100.0; c = cos(a); s = sin(a); }
    ct[2 * m]     = c * 0.01;   // forward norm 1/100 folded in
    ct[2 * m + 1] = s * 0.01;
  }
}

// =================== fused encoder + 50-step GRU decoder ===================
// block: 512 thr (8 waves), 256 rows. wave = (mq in 0..3: 4 M-tiles of 16 rows) x (jh: j-half).
__global__ __launch_bounds__(512, 2) void fused_kernel(
    const float* __restrict__ enc_in, const unsigned char* __restrict__ ws,
    float* __restrict__ out)
{
  __shared__ __align__(16) unsigned char smem[SMEM_BYTES];
  _Float16* Hb    = (_Float16*)smem;                 // [256][212]
  _Float16* Y1    = (_Float16*)(smem + 108544);      // [256][104]
  float*    DECIN = (float*)(smem + 161792);         // [256]
  float*    XF    = (float*)(smem + 108544);         // [64][101]
  _Float16* X1    = (_Float16*)(smem + 108544);      // [64][104] (after DFT)
  _Float16* SIG   = (_Float16*)(smem + 134400);      // [64][212]; X2 overlays after enc1
  _Float16* X2    = SIG;
  const double* CT = (const double*)(smem + 161536); // [100][2]

  const _Float16* Wbig = (const _Float16*)(ws + WBIG_OFF);
  const _Float16* W2w  = (const _Float16*)(ws + W2_OFF);
  const _Float16* We1  = (const _Float16*)(ws + WE1_OFF);
  const _Float16* We2  = (const _Float16*)(ws + WE2_OFF);
  const _Float16* Wel  = (const _Float16*)(ws + WEL_OFF);
  const float* wihc = (const float*)(ws + WIHC_OFF);
  const float* bsum = (const float*)(ws + BSUM_OFF);
  const float* bhhn = (const float*)(ws + BHHN_OFF);
  const float* b1p  = (const float*)(ws + B1P_OFF);
  const float* b2p  = (const float*)(ws + B2P_OFF);
  const float* w3p  = (const float*)(ws + W3P_OFF);
  const float* be1  = (const float*)(ws + BE1_OFF);
  const float* be2  = (const float*)(ws + BE2_OFF);
  const float* bel  = (const float*)(ws + BEL_OFF);
  const float b3v   = *(const float*)(ws + B3_OFF);

  const int tid = threadIdx.x;
  const int lane = tid & 63, wv = tid >> 6;
  const int q = lane >> 4, c = lane & 15;
  const int mq = wv >> 1, jh = wv & 1;
  const int row0 = blockIdx.x * 256;
  const half8 Z8 = {};

  // zero h K-pad cols 200..211 (persist: h_new writes are masked to col<200)
  for (int i = tid; i < 256 * 12; i += 512) {
    int r = i / 12; Hb[r * 212 + 200 + (i - r * 12)] = (_Float16)0.f;
  }
  // twiddles -> LDS
  {
    double* ctl = (double*)(smem + 161536);
    const double* ctg = (const double*)(ws + CT_OFF);
    for (int i = tid; i < 200; i += 512) ctl[i] = ctg[i];
  }

  // ---------------- ENCODER: 4 sub-rounds of 64 rows ----------------
  for (int sub = 0; sub < 4; ++sub) {
    __syncthreads();   // also covers init stores / prev sub's X2 reads
    for (int i = tid; i < 6400; i += 512) {
      int r = i / 100, t = i - r * 100;
      float v = enc_in[(size_t)(row0 + sub * 64 + r) * 100 + t];
      XF[r * 101 + t] = v;
      SIG[r * 212 + t] = (_Float16)v;
    }
    for (int i = tid; i < 640; i += 512) {           // zero sig cols 202..211
      int r = i / 10; SIG[r * 212 + 202 + (i - r * 10)] = (_Float16)0.f;
    }
    __syncthreads();
    // --- fp64 DFT (sign-safe angles); lane = row, wave-uniform bin ---
    for (int kb = wv; kb < 51; kb += 8) {
      double re = 0.0, im = 0.0; int m = 0;
      const float* xr = XF + lane * 101;
      for (int t = 0; t < 100; ++t) {
        double x = (double)xr[t];
        re = fma(x, CT[2 * m], re);
        im = fma(x, CT[2 * m + 1], im);
        m += kb; if (m >= 100) m -= 100;
      }
      if (kb == 0 || kb == 50) im = 0.0;             // match pocketfft exact-real DC/Nyquist
      float ab = (float)sqrt(re * re + im * im);
      float an = atan2f((float)im, (float)re);
      SIG[lane * 212 + 100 + kb] = (_Float16)ab;
      SIG[lane * 212 + 151 + kb] = (_Float16)an;
    }
    __syncthreads();
    // --- enc1: sig(K202->7s) -> x1 ---
    {
      half8 Ae[7];
      const _Float16* sp = SIG + (mq * 16 + c) * 212 + q * 8;
#pragma unroll
      for (int s = 0; s < 7; ++s) Ae[s] = (s == 6 && q >= 2) ? Z8 : lds_frag(sp + s * 32);
      int jt0 = jh ? 4 : 0, jt1 = jh ? 7 : 4;
#pragma unroll 1
      for (int jt = jt0; jt < jt1; ++jt) {
        floatx4 C = {0.f, 0.f, 0.f, 0.f};
        const _Float16* wp = We1 + (jt * 16 + c) * 224 + q * 8;
#pragma unroll
        for (int s = 0; s < 7; ++s) C = MFMA16(Ae[s], g_frag(wp + s * 32), C);
        int col = jt * 16 + c; float bv = be1[col]; bool wm = col < 104;
#pragma unroll
        for (int r = 0; r < 4; ++r) {
          float v = C[r] + bv; v = fmaxf(v, 0.01f * v);
          if (wm) X1[(mq * 16 + 4 * q + r) * 104 + col] = (_Float16)v;
        }
      }
    }
    __syncthreads();
    // --- enc2: x1(K100->4s masked) -> x2 (overlays SIG) ---
    {
      half8 Ax[4];
      const _Float16* xp = X1 + (mq * 16 + c) * 104 + q * 8;
#pragma unroll
      for (int s = 0; s < 4; ++s) Ax[s] = (s == 3 && q >= 1) ? Z8 : lds_frag(xp + s * 32);
      int jt0 = jh ? 7 : 0, jt1 = jh ? 13 : 7;
#pragma unroll 1
      for (int jt = jt0; jt < jt1; ++jt) {
        floatx4 C = {0.f, 0.f, 0.f, 0.f};
        const _Float16* wp = We2 + (jt * 16 + c) * 128 + q * 8;
#pragma unroll
        for (int s = 0; s < 4; ++s) C = MFMA16(Ax[s], g_frag(wp + s * 32), C);
        int col = jt * 16 + c; float bv = be2[col];
#pragma unroll
        for (int r = 0; r < 4; ++r) {
          float v = C[r] + bv; v = fmaxf(v, 0.01f * v);
          X2[(mq * 16 + 4 * q + r) * 212 + col] = (_Float16)v;
        }
      }
    }
    __syncthreads();
    // --- encl: x2(K202->7s) -> h0 rows (no activation) ---
    {
      half8 Ax[7];
      const _Float16* xp = X2 + (mq * 16 + c) * 212 + q * 8;
#pragma unroll
      for (int s = 0; s < 7; ++s) Ax[s] = (s == 6 && q >= 2) ? Z8 : lds_frag(xp + s * 32);
      int jt0 = jh ? 7 : 0, jt1 = jh ? 13 : 7;
#pragma unroll 1
      for (int jt = jt0; jt < jt1; ++jt) {
        floatx4 C = {0.f, 0.f, 0.f, 0.f};
        const _Float16* wp = Wel + (jt * 16 + c) * 224 + q * 8;
#pragma unroll
        for (int s = 0; s < 7; ++s) C = MFMA16(Ax[s], g_frag(wp + s * 32), C);
        int col = jt * 16 + c; float bv = bel[col]; bool wm = col < 200;
#pragma unroll
        for (int r = 0; r < 4; ++r) {
          float v = C[r] + bv;
          if (wm) Hb[(sub * 64 + mq * 16 + 4 * q + r) * 212 + col] = (_Float16)v;
        }
      }
    }
  }
  __syncthreads();                       // encoder done (CT now dead)
  for (int i = tid; i < 256; i += 512)
    DECIN[i] = enc_in[(size_t)(row0 + i) * 100 + 99];
  __syncthreads();

  // ---------------- DECODER: 51 iterations ----------------
  half8 A[4][7];
#pragma unroll 1
  for (int k = 0; k <= 50; ++k) {
    // persistent A-frags of h_k (reused by y1 GEMM and gate GEMMs)
#pragma unroll
    for (int m = 0; m < 4; ++m) {
      const _Float16* hp = Hb + (mq * 64 + m * 16 + c) * 212 + q * 8;
#pragma unroll
      for (int s = 0; s < 7; ++s)
        A[m][s] = (s == 6 && q >= 2) ? Z8 : lds_frag(hp + s * 32);
    }
    if (k >= 1) {
      // ---- phase A: y1 = lrelu(h_k @ dec_w1^T + b1) ----
      {
        int jt0 = jh ? 4 : 0, jt1 = jh ? 7 : 4;
#pragma unroll 1
        for (int jt = jt0; jt < jt1; ++jt) {
          floatx4 C[4] = {{0.f,0.f,0.f,0.f},{0.f,0.f,0.f,0.f},{0.f,0.f,0.f,0.f},{0.f,0.f,0.f,0.f}};
          const _Float16* wp = Wbig + (624 + jt * 16 + c) * 224 + q * 8;
#pragma unroll
          for (int s = 0; s < 7; ++s) {
            half8 B = g_frag(wp + s * 32);
#pragma unroll
            for (int m = 0; m < 4; ++m) C[m] = MFMA16(A[m][s], B, C[m]);
          }
          int col = jt * 16 + c; float bv = b1p[col]; bool wm = col < 104;
#pragma unroll
          for (int m = 0; m < 4; ++m)
#pragma unroll
            for (int r = 0; r < 4; ++r) {
              float v = C[m][r] + bv; v = fmaxf(v, 0.01f * v);
              if (wm) Y1[(mq * 64 + m * 16 + 4 * q + r) * 104 + col] = (_Float16)v;
            }
        }
      }
      __syncthreads();
      // ---- phase B: y2 -> y3 -> y_{k-1} (output + next dec_in) ----
      {
        float ya[2][4] = {{0.f,0.f,0.f,0.f},{0.f,0.f,0.f,0.f}};
#pragma unroll
        for (int ml = 0; ml < 2; ++ml) {
          const _Float16* yp = Y1 + (mq * 64 + (jh * 2 + ml) * 16 + c) * 104 + q * 8;
          half8 A2[4];
#pragma unroll
          for (int s = 0; s < 4; ++s) A2[s] = (s == 3 && q >= 1) ? Z8 : lds_frag(yp + s * 32);
#pragma unroll
          for (int jt = 0; jt < 4; ++jt) {
            floatx4 Cy = {0.f, 0.f, 0.f, 0.f};
            const _Float16* wp = W2w + (jt * 16 + c) * 128 + q * 8;
#pragma unroll
            for (int s = 0; s < 4; ++s) Cy = MFMA16(A2[s], g_frag(wp + s * 32), Cy);
            int col = jt * 16 + c; float b2v = b2p[col], w3v = w3p[col];
#pragma unroll
            for (int r = 0; r < 4; ++r) {
              float v = Cy[r] + b2v; v = fmaxf(v, 0.01f * v);
              ya[ml][r] = fmaf(v, w3v, ya[ml][r]);
            }
          }
        }
#pragma unroll
        for (int ml = 0; ml < 2; ++ml)
#pragma unroll
          for (int r = 0; r < 4; ++r) {
            float v = ya[ml][r];
            v += __shfl_xor(v, 1); v += __shfl_xor(v, 2);
            v += __shfl_xor(v, 4); v += __shfl_xor(v, 8);
            ya[ml][r] = v;
          }
        if (c == 0) {
#pragma unroll
          for (int ml = 0; ml < 2; ++ml)
#pragma unroll
            for (int r = 0; r < 4; ++r) {
              int rowL = mq * 64 + jh * 32 + ml * 16 + 4 * q + r;
              float y = ya[ml][r] + b3v;
              DECIN[rowL] = y;
              out[(size_t)(row0 + rowL) * 50 + (k - 1)] = y;
            }
        }
      }
      __syncthreads();
    } else {
      __syncthreads();   // k==0: A-loads complete before phase C writes
    }
    if (k <= 49) {
      // ---- phase C: 3-gate GEMM + GRU update (h_k -> h_{k+1}, tile-local r/w) ----
      float dreg[16];
#pragma unroll
      for (int m = 0; m < 4; ++m)
#pragma unroll
        for (int r = 0; r < 4; ++r)
          dreg[m * 4 + r] = DECIN[mq * 64 + m * 16 + 4 * q + r];
      int jt0 = jh ? 7 : 0, jt1 = jh ? 13 : 7;
#pragma unroll 1
      for (int jt = jt0; jt < jt1; ++jt) {
        floatx4 Cr[4], Cz[4], Cn[4];
#pragma unroll
        for (int m = 0; m < 4; ++m) {
          Cr[m] = (floatx4){0.f,0.f,0.f,0.f};
          Cz[m] = (floatx4){0.f,0.f,0.f,0.f};
          Cn[m] = (floatx4){0.f,0.f,0.f,0.f};
        }
        const _Float16* wp = Wbig + (jt * 16 + c) * 224 + q * 8;
#pragma unroll
        for (int s = 0; s < 7; ++s) {
          half8 Br = g_frag(wp + s * 32);
          half8 Bz = g_frag(wp + 208 * 224 + s * 32);
          half8 Bn = g_frag(wp + 416 * 224 + s * 32);
#pragma unroll
          for (int m = 0; m < 4; ++m) {
            Cr[m] = MFMA16(A[m][s], Br, Cr[m]);
            Cz[m] = MFMA16(A[m][s], Bz, Cz[m]);
            Cn[m] = MFMA16(A[m][s], Bn, Cn[m]);
          }
        }
        int col = jt * 16 + c;
        float wr = wihc[col], wz = wihc[208 + col], wn = wihc[416 + col];
        float br = bsum[col], bz = bsum[208 + col], bnih = bsum[416 + col];
        float bnhh = bhhn[col];
        bool wm = col < 200;
#pragma unroll
        for (int m = 0; m < 4; ++m) {
          int rbase = (mq * 64 + m * 16 + 4 * q) * 212 + col;
#pragma unroll
          for (int r = 0; r < 4; ++r) {
            float d  = dreg[m * 4 + r];
            float rg = sigm(Cr[m][r] + fmaf(d, wr, br));
            float zg = sigm(Cz[m][r] + fmaf(d, wz, bz));
            float ng = tanh_(fmaf(d, wn, bnih) + rg * (Cn[m][r] + bnhh));
            float ho = (float)Hb[rbase + r * 212];
            float hv = fmaf(zg, ho - ng, ng);
            if (wm) Hb[rbase + r * 212] = (_Float16)hv;
          }
        }
      }
    }
    __syncthreads();
  }
}

extern "C" void kernel_launch(void* const* d_in, const int* in_sizes, int n_in,
                              void* d_out, int out_size, void* d_ws, size_t ws_size,
                              hipStream_t stream) {
  const float* enc_in = (const float*)d_in[0];
  const float* enc_w1 = (const float*)d_in[1];
  const float* enc_b1 = (const float*)d_in[2];
  const float* enc_w2 = (const float*)d_in[3];
  const float* enc_b2 = (const float*)d_in[4];
  const float* enc_wl = (const float*)d_in[5];
  const float* enc_bl = (const float*)d_in[6];
  const float* w_ih   = (const float*)d_in[7];
  const float* w_hh   = (const float*)d_in[8];
  const float* b_ih   = (const float*)d_in[9];
  const float* b_hh   = (const float*)d_in[10];
  const float* dw1    = (const float*)d_in[11];
  const float* db1    = (const float*)d_in[12];
  const float* dw2    = (const float*)d_in[13];
  const float* db2    = (const float*)d_in[14];
  const float* dw3    = (const float*)d_in[15];
  const float* db3    = (const float*)d_in[16];
  unsigned char* ws = (unsigned char*)d_ws;
  float* out = (float*)d_out;

  prep_kernel<<<dim3(256), dim3(256), 0, stream>>>(
      enc_w1, enc_b1, enc_w2, enc_b2, enc_wl, enc_bl,
      w_ih, w_hh, b_ih, b_hh, dw1, db1, dw2, db2, dw3, db3, ws);
  fused_kernel<<<dim3(512), dim3(512), 0, stream>>>(enc_in, ws, out);
}